// Round 3
// baseline (6606.953 us; speedup 1.0000x reference)
//
#include <hip/hip_runtime.h>

#define SEQn   1024
#define BATCHn 64
#define EMBn   256
#define HIDn   512
#define VOCn   512

#define NL1 32
#define NL2 32
#define NFC 8
#define NBLK (NL1 + NL2 + NFC)   /* 72 fat blocks: halves sc1 read volume */
#define NPHASE (SEQn + 2)        /* 1026 phases: skewed L1 / L2 / FC pipeline */
#define HBUF (BATCHn * HIDn)     /* 32768 f16 = 64KB */

using f16   = _Float16;
using half8 = __attribute__((ext_vector_type(8))) _Float16;
using f32x4 = __attribute__((ext_vector_type(4))) float;
using i32x4 = __attribute__((ext_vector_type(4))) int;
using i32x2 = __attribute__((ext_vector_type(2))) int;

/* workspace layout (bytes) */
#define WS_FLG 0                            /* 72 monotonic phase flags   */
#define WS_H1  4096                         /* 4 rep x 2 par x 64KB       */
#define WS_H2  (WS_H1 + 8 * HBUF * 2)
#define WS_P1  (WS_H2 + 8 * HBUF * 2)       /* [512][2048] f16, 2MB       */

/* ---- tiled h layout ----
   h[mblk(4)][ks(16)][qq(4)][cc(16)][8 f16]  (64KB total)
   element (row r, col c) -> f16 index
     (((r>>4)*16 + (c>>5))*4 + ((c>>3)&3))*128 + (r&15)*8 + (c&7)
   A-fragment load for wave row-block W, lane l=qq*16+cc, slice ks:
     base = W*8192 + l*8, stride ks*512   -> lane-contiguous dwordx4.   */

__device__ __forceinline__ float sigm_(float v) { return 1.0f / (1.0f + __expf(-v)); }
__device__ __forceinline__ float tanh_(float v) { return 1.0f - 2.0f / (__expf(2.0f * v) + 1.0f); }

__device__ __forceinline__ void st_u32_sc1(f16* p, unsigned v) {
  asm volatile("global_store_dword %0, %1, off sc1" :: "v"(p), "v"(v) : "memory");
}
__device__ __forceinline__ void st_b64_sc1(f16* p, i32x2 v) {
  asm volatile("global_store_dwordx2 %0, %1, off sc1" :: "v"(p), "v"(v) : "memory");
}
__device__ __forceinline__ void st_b128_sc1(f16* p, f32x4 v) {
  asm volatile("global_store_dwordx4 %0, %1, off sc1" :: "v"(p), "v"(v) : "memory");
}
__device__ __forceinline__ unsigned pack2(float a, float b) {
  f16 lo = (f16)a, hi = (f16)b;
  return (unsigned)__builtin_bit_cast(unsigned short, lo)
       | ((unsigned)__builtin_bit_cast(unsigned short, hi) << 16);
}

/* 16 x dwordx4 device-scope (sc1) loads + drain in ONE asm block: the
   s_waitcnt lives inside the asm, so no compiler-placed copy or hoisted
   MFMA can read an in-flight VMEM destination. Covers one 16KB M-block. */
__device__ __forceinline__ void ld_frag16(const f16* base, half8 (&a)[16]) {
  const f16* b0 = base + 2048;   /* +4KB  : ks 0..7 via signed offsets  */
  const f16* b1 = base + 6144;   /* +12KB : ks 8..15                    */
  f32x4 t0,t1,t2,t3,t4,t5,t6,t7,t8,t9,t10,t11,t12,t13,t14,t15;
  asm volatile(
    "global_load_dwordx4 %0,  %16, off offset:-4096 sc1\n\t"
    "global_load_dwordx4 %1,  %16, off offset:-3072 sc1\n\t"
    "global_load_dwordx4 %2,  %16, off offset:-2048 sc1\n\t"
    "global_load_dwordx4 %3,  %16, off offset:-1024 sc1\n\t"
    "global_load_dwordx4 %4,  %16, off sc1\n\t"
    "global_load_dwordx4 %5,  %16, off offset:1024 sc1\n\t"
    "global_load_dwordx4 %6,  %16, off offset:2048 sc1\n\t"
    "global_load_dwordx4 %7,  %16, off offset:3072 sc1\n\t"
    "global_load_dwordx4 %8,  %17, off offset:-4096 sc1\n\t"
    "global_load_dwordx4 %9,  %17, off offset:-3072 sc1\n\t"
    "global_load_dwordx4 %10, %17, off offset:-2048 sc1\n\t"
    "global_load_dwordx4 %11, %17, off offset:-1024 sc1\n\t"
    "global_load_dwordx4 %12, %17, off sc1\n\t"
    "global_load_dwordx4 %13, %17, off offset:1024 sc1\n\t"
    "global_load_dwordx4 %14, %17, off offset:2048 sc1\n\t"
    "global_load_dwordx4 %15, %17, off offset:3072 sc1\n\t"
    "s_waitcnt vmcnt(0)"
    : "=&v"(t0),"=&v"(t1),"=&v"(t2),"=&v"(t3),
      "=&v"(t4),"=&v"(t5),"=&v"(t6),"=&v"(t7),
      "=&v"(t8),"=&v"(t9),"=&v"(t10),"=&v"(t11),
      "=&v"(t12),"=&v"(t13),"=&v"(t14),"=&v"(t15)
    : "v"(b0), "v"(b1)
    : "memory");
  a[0]  = __builtin_bit_cast(half8, t0);   a[1]  = __builtin_bit_cast(half8, t1);
  a[2]  = __builtin_bit_cast(half8, t2);   a[3]  = __builtin_bit_cast(half8, t3);
  a[4]  = __builtin_bit_cast(half8, t4);   a[5]  = __builtin_bit_cast(half8, t5);
  a[6]  = __builtin_bit_cast(half8, t6);   a[7]  = __builtin_bit_cast(half8, t7);
  a[8]  = __builtin_bit_cast(half8, t8);   a[9]  = __builtin_bit_cast(half8, t9);
  a[10] = __builtin_bit_cast(half8, t10);  a[11] = __builtin_bit_cast(half8, t11);
  a[12] = __builtin_bit_cast(half8, t12);  a[13] = __builtin_bit_cast(half8, t13);
  a[14] = __builtin_bit_cast(half8, t14);  a[15] = __builtin_bit_cast(half8, t15);
}

/* 32-load variant for L2: both M-blocks issued together, ONE round trip,
   single internal vmcnt(0) -> all outputs complete at asm end (no hazard). */
__device__ __forceinline__ void ld_frag32(const f16* baseA, const f16* baseB,
                                          half8 (&a)[16], half8 (&b)[16]) {
  const f16* a0 = baseA + 2048;  const f16* a1 = baseA + 6144;
  const f16* c0p = baseB + 2048; const f16* c1 = baseB + 6144;
  f32x4 t0,t1,t2,t3,t4,t5,t6,t7,t8,t9,t10,t11,t12,t13,t14,t15;
  f32x4 u0,u1,u2,u3,u4,u5,u6,u7,u8,u9,u10,u11,u12,u13,u14,u15;
  asm volatile(
    "global_load_dwordx4 %0,  %32, off offset:-4096 sc1\n\t"
    "global_load_dwordx4 %1,  %32, off offset:-3072 sc1\n\t"
    "global_load_dwordx4 %2,  %32, off offset:-2048 sc1\n\t"
    "global_load_dwordx4 %3,  %32, off offset:-1024 sc1\n\t"
    "global_load_dwordx4 %4,  %32, off sc1\n\t"
    "global_load_dwordx4 %5,  %32, off offset:1024 sc1\n\t"
    "global_load_dwordx4 %6,  %32, off offset:2048 sc1\n\t"
    "global_load_dwordx4 %7,  %32, off offset:3072 sc1\n\t"
    "global_load_dwordx4 %8,  %33, off offset:-4096 sc1\n\t"
    "global_load_dwordx4 %9,  %33, off offset:-3072 sc1\n\t"
    "global_load_dwordx4 %10, %33, off offset:-2048 sc1\n\t"
    "global_load_dwordx4 %11, %33, off offset:-1024 sc1\n\t"
    "global_load_dwordx4 %12, %33, off sc1\n\t"
    "global_load_dwordx4 %13, %33, off offset:1024 sc1\n\t"
    "global_load_dwordx4 %14, %33, off offset:2048 sc1\n\t"
    "global_load_dwordx4 %15, %33, off offset:3072 sc1\n\t"
    "global_load_dwordx4 %16, %34, off offset:-4096 sc1\n\t"
    "global_load_dwordx4 %17, %34, off offset:-3072 sc1\n\t"
    "global_load_dwordx4 %18, %34, off offset:-2048 sc1\n\t"
    "global_load_dwordx4 %19, %34, off offset:-1024 sc1\n\t"
    "global_load_dwordx4 %20, %34, off sc1\n\t"
    "global_load_dwordx4 %21, %34, off offset:1024 sc1\n\t"
    "global_load_dwordx4 %22, %34, off offset:2048 sc1\n\t"
    "global_load_dwordx4 %23, %34, off offset:3072 sc1\n\t"
    "global_load_dwordx4 %24, %35, off offset:-4096 sc1\n\t"
    "global_load_dwordx4 %25, %35, off offset:-3072 sc1\n\t"
    "global_load_dwordx4 %26, %35, off offset:-2048 sc1\n\t"
    "global_load_dwordx4 %27, %35, off offset:-1024 sc1\n\t"
    "global_load_dwordx4 %28, %35, off sc1\n\t"
    "global_load_dwordx4 %29, %35, off offset:1024 sc1\n\t"
    "global_load_dwordx4 %30, %35, off offset:2048 sc1\n\t"
    "global_load_dwordx4 %31, %35, off offset:3072 sc1\n\t"
    "s_waitcnt vmcnt(0)"
    : "=&v"(t0),"=&v"(t1),"=&v"(t2),"=&v"(t3),
      "=&v"(t4),"=&v"(t5),"=&v"(t6),"=&v"(t7),
      "=&v"(t8),"=&v"(t9),"=&v"(t10),"=&v"(t11),
      "=&v"(t12),"=&v"(t13),"=&v"(t14),"=&v"(t15),
      "=&v"(u0),"=&v"(u1),"=&v"(u2),"=&v"(u3),
      "=&v"(u4),"=&v"(u5),"=&v"(u6),"=&v"(u7),
      "=&v"(u8),"=&v"(u9),"=&v"(u10),"=&v"(u11),
      "=&v"(u12),"=&v"(u13),"=&v"(u14),"=&v"(u15)
    : "v"(a0), "v"(a1), "v"(c0p), "v"(c1)
    : "memory");
  a[0]  = __builtin_bit_cast(half8, t0);   a[1]  = __builtin_bit_cast(half8, t1);
  a[2]  = __builtin_bit_cast(half8, t2);   a[3]  = __builtin_bit_cast(half8, t3);
  a[4]  = __builtin_bit_cast(half8, t4);   a[5]  = __builtin_bit_cast(half8, t5);
  a[6]  = __builtin_bit_cast(half8, t6);   a[7]  = __builtin_bit_cast(half8, t7);
  a[8]  = __builtin_bit_cast(half8, t8);   a[9]  = __builtin_bit_cast(half8, t9);
  a[10] = __builtin_bit_cast(half8, t10);  a[11] = __builtin_bit_cast(half8, t11);
  a[12] = __builtin_bit_cast(half8, t12);  a[13] = __builtin_bit_cast(half8, t13);
  a[14] = __builtin_bit_cast(half8, t14);  a[15] = __builtin_bit_cast(half8, t15);
  b[0]  = __builtin_bit_cast(half8, u0);   b[1]  = __builtin_bit_cast(half8, u1);
  b[2]  = __builtin_bit_cast(half8, u2);   b[3]  = __builtin_bit_cast(half8, u3);
  b[4]  = __builtin_bit_cast(half8, u4);   b[5]  = __builtin_bit_cast(half8, u5);
  b[6]  = __builtin_bit_cast(half8, u6);   b[7]  = __builtin_bit_cast(half8, u7);
  b[8]  = __builtin_bit_cast(half8, u8);   b[9]  = __builtin_bit_cast(half8, u9);
  b[10] = __builtin_bit_cast(half8, u10);  b[11] = __builtin_bit_cast(half8, u11);
  b[12] = __builtin_bit_cast(half8, u12);  b[13] = __builtin_bit_cast(half8, u13);
  b[14] = __builtin_bit_cast(half8, u14);  b[15] = __builtin_bit_cast(half8, u15);
}

/* ---- init: zero flags, seed all h1/h2 replicas (tiled layout) ---- */
__global__ void k_init(const float* __restrict__ h0, char* __restrict__ ws) {
  int i = blockIdx.x * 256 + threadIdx.x;          /* grid 1024*256 = 262144 */
  f16* h1b = (f16*)(ws + WS_H1);
  f16* h2b = (f16*)(ws + WS_H2);
  int e = i & (HBUF - 1);
  int r = e >> 9, c = e & 511;
  float v = h0[e];
  int t = (((r >> 4) * 16 + (c >> 5)) * 4 + ((c >> 3) & 3)) * 128 + (r & 15) * 8 + (c & 7);
  int b = i & ~(HBUF - 1);
  h1b[b + t] = (f16)v;
  h2b[b + t] = (f16)v;
  if (i < 1024) ((int*)ws)[i] = 0;
}

/* ---- P1[v][g] = emb[v] . Wih1[g] + bih1[g] + bhh1[g]  (fp16) ---- */
__global__ void k_p1(const float* __restrict__ emb, const float* __restrict__ Wih1,
                     const float* __restrict__ bih1, const float* __restrict__ bhh1,
                     char* __restrict__ ws) {
  __shared__ float elds[32 * 256];
  int tid = threadIdx.x;
  int vb = blockIdx.x >> 5, gb = blockIdx.x & 31;  /* grid 512 */
  for (int i = tid; i < 32 * 256; i += 256) elds[i] = emb[vb * 32 * 256 + i];
  __syncthreads();
  int gl = tid & 63, vs = tid >> 6;
  int g = gb * 64 + gl;
  float bias = bih1[g] + bhh1[g];
  float acc[8];
#pragma unroll
  for (int r = 0; r < 8; ++r) acc[r] = bias;
  const float* wrow = Wih1 + g * EMBn;
#pragma unroll 4
  for (int e = 0; e < EMBn; ++e) {
    float w = wrow[e];
#pragma unroll
    for (int r = 0; r < 8; ++r) acc[r] += elds[(vs * 8 + r) * 256 + e] * w;
  }
  f16* P1 = (f16*)(ws + WS_P1);
#pragma unroll
  for (int r = 0; r < 8; ++r) P1[(vb * 32 + vs * 8 + r) * 2048 + g] = (f16)acc[r];
}

/* ---- persistent skewed-pipeline kernel ---- */
__global__ void __launch_bounds__(256, 1)
k_lstm(const int* __restrict__ x, const float* __restrict__ c0,
       const float* __restrict__ Whh1,
       const float* __restrict__ Wih2, const float* __restrict__ Whh2,
       const float* __restrict__ bih2, const float* __restrict__ bhh2,
       const float* __restrict__ Wfc, const float* __restrict__ bfc,
       float* __restrict__ out, char* __restrict__ ws)
{
  __shared__ float part[2][64][68];    /* L2 partial gates [K-half][row][4x16] */
  __shared__ f16 p1s[VOCn * 64];       /* L1 P1 slice [512 vocab][64 cols]     */
  __shared__ alignas(16) f16 hstage[4][2][16][8];  /* L1 h staging, 2KB        */

  f16* h1base = (f16*)(ws + WS_H1);
  f16* h2base = (f16*)(ws + WS_H2);
  const f16* P1 = (const f16*)(ws + WS_P1);

  const int bid = blockIdx.x, tid = threadIdx.x;
  const int lane = tid & 63, wv = tid >> 6;
  const int cc = lane & 15, qq = lane >> 4;
  const int rep = bid & 3;             /* which h replica this block reads */

  half8 bfrA[4][16];                   /* weight B-frags (i,f,g,o tiles), resident */
  float cst[4] = {0.f, 0.f, 0.f, 0.f};
  float bias[4] = {0.f, 0.f, 0.f, 0.f};
  int j0 = 0;
  /* L2 wave roles */
  const int khalf = wv >> 1;           /* 0: h1/Wih2, 1: h2/Whh2 */
  const int mh = wv & 1;               /* M 32-row half */

  if (bid < NL1) {
    /* layer-1: 16 units; tile nt = gate nt (i,f,g,o), col = unit cc */
    j0 = bid * 16;
#pragma unroll
    for (int nt = 0; nt < 4; ++nt) {
      const float* wr = Whh1 + (nt * 512 + j0 + cc) * HIDn;
#pragma unroll
      for (int ks = 0; ks < 16; ++ks) {
        const float* s = wr + ks * 32 + qq * 8;
        half8 hv;
#pragma unroll
        for (int j = 0; j < 8; ++j) hv[j] = (f16)s[j];
        bfrA[nt][ks] = hv;
      }
    }
    for (int i = tid; i < VOCn * 64; i += 256) {
      int v = i >> 6, n = i & 63;
      p1s[i] = P1[v * 2048 + (n >> 4) * 512 + j0 + (n & 15)];
    }
#pragma unroll
    for (int r = 0; r < 4; ++r)
      cst[r] = c0[(wv * 16 + qq * 4 + r) * HIDn + j0 + cc];
  } else if (bid < NL1 + NL2) {
    /* layer-2: 16 units; waves split (K-half x M-half) */
    j0 = (bid - NL1) * 16;
    const float* W = khalf ? Whh2 : Wih2;
#pragma unroll
    for (int nt = 0; nt < 4; ++nt) {
      const float* wr = W + (nt * 512 + j0 + cc) * HIDn;
#pragma unroll
      for (int ks = 0; ks < 16; ++ks) {
        const float* s = wr + ks * 32 + qq * 8;
        half8 hv;
#pragma unroll
        for (int j = 0; j < 8; ++j) hv[j] = (f16)s[j];
        bfrA[nt][ks] = hv;
      }
    }
    if (khalf == 0) {
#pragma unroll
      for (int nt = 0; nt < 4; ++nt) {
        int g = nt * 512 + j0 + cc;
        bias[nt] = bih2[g] + bhh2[g];
      }
    }
    /* epilogue cell state: thread owns (m = tid>>2, units us..us+3) */
    {
      int m = tid >> 2, us = (tid & 3) * 4;
#pragma unroll
      for (int w2 = 0; w2 < 4; ++w2)
        cst[w2] = c0[m * HIDn + j0 + us + w2];
    }
  } else {
    /* FC: 64 vocab cols */
    j0 = (bid - NL1 - NL2) * 64;
#pragma unroll
    for (int nt = 0; nt < 4; ++nt) {
      const float* wr = Wfc + (j0 + nt * 16 + cc) * HIDn;
#pragma unroll
      for (int ks = 0; ks < 16; ++ks) {
        const float* s = wr + ks * 32 + qq * 8;
        half8 hv;
#pragma unroll
        for (int j = 0; j < 8; ++j) hv[j] = (f16)s[j];
        bfrA[nt][ks] = hv;
      }
      bias[nt] = bfc[j0 + nt * 16 + cc];
    }
  }
  /* per-block unit window inside the tiled ks/qq grid (L1/L2: 16 units) */
  const int ksJ = (j0 >> 5), qqJ = (j0 >> 3) & 3;
  __syncthreads();

  /* L1: pre-gather the x/P1 accumulator for phase 1 */
  f32x4 pg[4];
  if (bid < NL1) {
#pragma unroll
    for (int r = 0; r < 4; ++r) {
      int xv = x[wv * 16 + qq * 4 + r];
#pragma unroll
      for (int t = 0; t < 4; ++t)
        pg[t][r] = (float)p1s[xv * 64 + t * 16 + cc];
    }
  }

  for (int p = 1; p <= NPHASE; ++p) {
    if (bid < NL1) {
      if (p <= SEQn) {                 /* h1_p = f(h1_{p-1}, x_{p-1}) */
        const f16* hp = h1base + (rep * 2 + ((p - 1) & 1)) * HBUF;
        f32x4 acc[4];
#pragma unroll
        for (int t = 0; t < 4; ++t) acc[t] = pg[t];
        half8 a[16];
        ld_frag16(hp + wv * 8192 + lane * 8, a);
#pragma unroll
        for (int ks = 0; ks < 16; ++ks) {
#pragma unroll
          for (int t = 0; t < 4; ++t)
            acc[t] = __builtin_amdgcn_mfma_f32_16x16x32_f16(a[ks], bfrA[t][ks], acc[t], 0, 0, 0);
        }
        /* all gates in-lane now: acc0=i acc1=f acc2=g acc3=o, unit cc */
        float hv4[4];
#pragma unroll
        for (int r = 0; r < 4; ++r) {
          float iv = sigm_(acc[0][r]);
          float ff = sigm_(acc[1][r]);
          float gv = tanh_(acc[2][r]);
          float oo = sigm_(acc[3][r]);
          float cn = ff * cst[r] + iv * gv;
          cst[r] = cn;
          hv4[r] = oo * tanh_(cn);
        }
        /* stage h through LDS -> 2 dense dwordx4 stores per thread (4 reps) */
#pragma unroll
        for (int r = 0; r < 4; ++r)
          hstage[wv][cc >> 3][qq * 4 + r][cc & 7] = (f16)hv4[r];
        __syncthreads();
        {
          int tp = tid & 127, rp0 = tid >> 7;
          f32x4 w = ((const f32x4*)hstage)[tp];
          int mb = tp >> 5, uh = (tp >> 4) & 1, r15 = tp & 15;
          int dst16 = mb * 8192 + ksJ * 512 + (qqJ + uh) * 128 + r15 * 8;
          st_b128_sc1(h1base + (rp0 * 2 + (p & 1)) * HBUF + dst16, w);
          st_b128_sc1(h1base + ((rp0 + 2) * 2 + (p & 1)) * HBUF + dst16, w);
        }
      }
    } else if (bid < NL1 + NL2) {
      if (p >= 2 && p <= SEQn + 1) {   /* h2_{p-1} = f(h1_{p-1}, h2_{p-2}) */
        const f16* src = (khalf == 0)
            ? h1base + (rep * 2 + ((p - 1) & 1)) * HBUF
            : h2base + (rep * 2 + (p & 1)) * HBUF;
        half8 a0[16], a1[16];
        ld_frag32(src + (mh * 2 + 0) * 8192 + lane * 8,
                  src + (mh * 2 + 1) * 8192 + lane * 8, a0, a1);
        f32x4 acc[2][4];
#pragma unroll
        for (int mt = 0; mt < 2; ++mt)
#pragma unroll
          for (int nt = 0; nt < 4; ++nt)
#pragma unroll
            for (int r = 0; r < 4; ++r)
              acc[mt][nt][r] = (khalf == 0) ? bias[nt] : 0.f;
#pragma unroll
        for (int ks = 0; ks < 16; ++ks) {
#pragma unroll
          for (int nt = 0; nt < 4; ++nt) {
            acc[0][nt] = __builtin_amdgcn_mfma_f32_16x16x32_f16(a0[ks], bfrA[nt][ks], acc[0][nt], 0, 0, 0);
            acc[1][nt] = __builtin_amdgcn_mfma_f32_16x16x32_f16(a1[ks], bfrA[nt][ks], acc[1][nt], 0, 0, 0);
          }
        }
#pragma unroll
        for (int mt = 0; mt < 2; ++mt)
#pragma unroll
          for (int nt = 0; nt < 4; ++nt)
#pragma unroll
            for (int r = 0; r < 4; ++r)
              part[khalf][mh * 32 + mt * 16 + qq * 4 + r][nt * 16 + cc] = acc[mt][nt][r];
        __syncthreads();
        {
          int m = tid >> 2, us = (tid & 3) * 4;
          f16* ho = h2base + ((p - 1) & 1) * HBUF;  /* + rep offset below */
          f32x4 gi = *(const f32x4*)&part[0][m][us]      + *(const f32x4*)&part[1][m][us];
          f32x4 gf = *(const f32x4*)&part[0][m][16 + us] + *(const f32x4*)&part[1][m][16 + us];
          f32x4 gg = *(const f32x4*)&part[0][m][32 + us] + *(const f32x4*)&part[1][m][32 + us];
          f32x4 go = *(const f32x4*)&part[0][m][48 + us] + *(const f32x4*)&part[1][m][48 + us];
          float hh[4];
#pragma unroll
          for (int w2 = 0; w2 < 4; ++w2) {
            float cn = sigm_(gf[w2]) * cst[w2] + sigm_(gi[w2]) * tanh_(gg[w2]);
            cst[w2] = cn;
            hh[w2] = sigm_(go[w2]) * tanh_(cn);
          }
          i32x2 v;
          v[0] = (int)pack2(hh[0], hh[1]);
          v[1] = (int)pack2(hh[2], hh[3]);
          int off = (m >> 4) * 8192 + ksJ * 512 + (qqJ + (us >> 3)) * 128
                  + (m & 15) * 8 + (us & 7);
#pragma unroll
          for (int rp = 0; rp < 4; ++rp)
            st_b64_sc1(ho + rp * 2 * HBUF + off, v);
        }
      }
    } else {
      if (p >= 3) {                    /* out_{p-3} = h2_{p-2} @ WfcT + bfc */
        const f16* h2p = h2base + (rep * 2 + (p & 1)) * HBUF;
        float* op = out + (size_t)(p - 3) * (BATCHn * VOCn);
        half8 a[16];
        ld_frag16(h2p + wv * 8192 + lane * 8, a);
        f32x4 acc[4];
#pragma unroll
        for (int nt = 0; nt < 4; ++nt)
#pragma unroll
          for (int r = 0; r < 4; ++r) acc[nt][r] = bias[nt];
#pragma unroll
        for (int ks = 0; ks < 16; ++ks) {
#pragma unroll
          for (int nt = 0; nt < 4; ++nt)
            acc[nt] = __builtin_amdgcn_mfma_f32_16x16x32_f16(a[ks], bfrA[nt][ks], acc[nt], 0, 0, 0);
        }
#pragma unroll
        for (int nt = 0; nt < 4; ++nt)
#pragma unroll
          for (int r = 0; r < 4; ++r) {
            int m = wv * 16 + qq * 4 + r;
            __builtin_nontemporal_store(acc[nt][r], &op[m * VOCn + j0 + nt * 16 + cc]);
          }
      }
    }

    /* ---- phase barrier: per-block monotonic flag + wave-parallel poll ----
       arrival: ONE sc1 dword store to own slot (no atomic RMW contention);
       detection: wave 0, lanes 0..17 load 4 flags each (dwordx4 sc1) and
       __all(flags >= p). Producers drain sc1 h-stores first so flag
       publication orders after data at the MALL coherence point. */
    if (bid < NL1 + NL2) asm volatile("s_waitcnt vmcnt(0)" ::: "memory");
    __syncthreads();
    if (tid == 0)
      asm volatile("global_store_dword %0, %1, off sc1"
                   :: "v"((int*)ws + bid), "v"(p) : "memory");
    /* L1: pre-gather next phase's x/P1 accumulator under the barrier wait */
    if (bid < NL1 && p < SEQn) {
#pragma unroll
      for (int r = 0; r < 4; ++r) {
        int xv = x[p * 64 + wv * 16 + qq * 4 + r];
#pragma unroll
        for (int t = 0; t < 4; ++t)
          pg[t][r] = (float)p1s[xv * 64 + t * 16 + cc];
      }
    }
    if (wv == 0) {
      const int* fp = (const int*)ws + (lane << 2);
      for (;;) {
        i32x4 f;
        asm volatile("global_load_dwordx4 %0, %1, off sc1\n\ts_waitcnt vmcnt(0)"
                     : "=v"(f) : "v"(fp) : "memory");
        int ok = (lane >= 18) ||
                 ((f[0] >= p) & (f[1] >= p) & (f[2] >= p) & (f[3] >= p));
        if (__all(ok)) break;
        __builtin_amdgcn_s_sleep(2);
      }
    }
    __syncthreads();
  }
}

extern "C" void kernel_launch(void* const* d_in, const int* in_sizes, int n_in,
                              void* d_out, int out_size, void* d_ws, size_t ws_size,
                              hipStream_t stream) {
  (void)in_sizes; (void)n_in; (void)out_size; (void)ws_size;
  const int*   x    = (const int*)  d_in[0];
  const float* h0   = (const float*)d_in[1];
  const float* c0   = (const float*)d_in[2];
  const float* emb  = (const float*)d_in[3];
  const float* Wih1 = (const float*)d_in[4];
  const float* Whh1 = (const float*)d_in[5];
  const float* bih1 = (const float*)d_in[6];
  const float* bhh1 = (const float*)d_in[7];
  const float* Wih2 = (const float*)d_in[8];
  const float* Whh2 = (const float*)d_in[9];
  const float* bih2 = (const float*)d_in[10];
  const float* bhh2 = (const float*)d_in[11];
  const float* Wfc  = (const float*)d_in[12];
  const float* bfc  = (const float*)d_in[13];
  char* ws = (char*)d_ws;

  hipLaunchKernelGGL(k_init, dim3(1024), dim3(256), 0, stream, h0, ws);
  hipLaunchKernelGGL(k_p1,   dim3(512), dim3(256), 0, stream, emb, Wih1, bih1, bhh1, ws);
  hipLaunchKernelGGL(k_lstm, dim3(NBLK), dim3(256), 0, stream,
                     x, c0, Whh1, Wih2, Whh2, bih2, bhh2, Wfc, bfc,
                     (float*)d_out, ws);
}

// Round 5
// 5303.571 us; speedup vs baseline: 1.2458x; 1.2458x over previous
//
#include <hip/hip_runtime.h>

#define SEQn   1024
#define BATCHn 64
#define EMBn   256
#define HIDn   512
#define VOCn   512

#define NGRP 4                   /* independent batch groups of 16 rows      */
#define NL1g 16                  /* per group: 16 L1 blocks x 32 units       */
#define NL2g 16                  /* 16 L2 blocks x 32 units                  */
#define NFCg 16                  /* 16 FC blocks x 32 vocab cols             */
#define GBLK (NL1g + NL2g + NFCg)            /* 48 blocks per group          */
#define NBLK (NGRP * GBLK)                   /* 192 blocks, <= 256 CUs       */
#define NPHASE (SEQn + 2)        /* 1026 phases: skewed L1 / L2 / FC pipeline */
#define HS 8192                  /* f16 per h-slice: 16 rows x 512 = 16KB    */

using f16   = _Float16;
using half8 = __attribute__((ext_vector_type(8))) _Float16;
using f32x4 = __attribute__((ext_vector_type(4))) float;
using i32x4 = __attribute__((ext_vector_type(4))) int;

/* workspace layout (bytes) */
#define WS_FLG 0                             /* 4 groups x 64-int flag rows  */
#define WS_H1  4096                          /* [grp4][par2][rep2][16KB]     */
#define WS_H2  (WS_H1 + NGRP * 4 * HS * 2)
#define WS_P1  (WS_H2 + NGRP * 4 * HS * 2)   /* [512][2048] f16, 2MB         */

/* ---- h-slice layout (per group, 16 rows x 512 cols) ----
   idx = ks*512 + qq*128 + cc*8 + e   <->  row = cc, col = ks*32 + qq*8 + e
   A-fragment load, lane l = qq*16+cc, slice ks: addr = ks*512 + l*8
   -> one lane-contiguous dwordx4 per ks (1KB per wave-instruction).       */

__device__ __forceinline__ float sigm_(float v) { return 1.0f / (1.0f + __expf(-v)); }
__device__ __forceinline__ float tanh_(float v) { return 1.0f - 2.0f / (__expf(2.0f * v) + 1.0f); }

__device__ __forceinline__ void st_b128_sc1(f16* p, f32x4 v) {
  asm volatile("global_store_dwordx4 %0, %1, off sc1" :: "v"(p), "v"(v) : "memory");
}

/* device-scope loads + drain inside ONE asm block (compiler cannot hoist a
   consumer past the internal s_waitcnt). Each covers this wave's K-slices. */
__device__ __forceinline__ void ld2_sc1(const f16* base, half8 (&a)[2]) {
  f32x4 t0, t1;
  asm volatile(
    "global_load_dwordx4 %0, %2, off sc1\n\t"
    "global_load_dwordx4 %1, %2, off offset:1024 sc1\n\t"
    "s_waitcnt vmcnt(0)"
    : "=&v"(t0), "=&v"(t1) : "v"(base) : "memory");
  a[0] = __builtin_bit_cast(half8, t0);
  a[1] = __builtin_bit_cast(half8, t1);
}
__device__ __forceinline__ void ld4_sc1(const f16* base, half8 (&a)[4]) {
  f32x4 t0, t1, t2, t3;
  asm volatile(
    "global_load_dwordx4 %0, %4, off sc1\n\t"
    "global_load_dwordx4 %1, %4, off offset:1024 sc1\n\t"
    "global_load_dwordx4 %2, %4, off offset:2048 sc1\n\t"
    "global_load_dwordx4 %3, %4, off offset:3072 sc1\n\t"
    "s_waitcnt vmcnt(0)"
    : "=&v"(t0), "=&v"(t1), "=&v"(t2), "=&v"(t3) : "v"(base) : "memory");
  a[0] = __builtin_bit_cast(half8, t0);
  a[1] = __builtin_bit_cast(half8, t1);
  a[2] = __builtin_bit_cast(half8, t2);
  a[3] = __builtin_bit_cast(half8, t3);
}

/* ---- init: zero flags, seed all group h1/h2 slices (both parities/reps) ---- */
__global__ void k_init(const float* __restrict__ h0, char* __restrict__ ws) {
  int i = blockIdx.x * 256 + threadIdx.x;          /* grid 512*256 = 131072 */
  f16* h1b = (f16*)(ws + WS_H1);
  f16* h2b = (f16*)(ws + WS_H2);
  int slice = i >> 13;                 /* g*4 + parity*2 + rep (16 slices)  */
  int off = i & (HS - 1);
  int g = slice >> 2;
  int ks = off >> 9, rem = off & 511;
  int qq = rem >> 7, cc = (rem >> 3) & 15, e = rem & 7;
  int row = g * 16 + cc, col = ks * 32 + qq * 8 + e;
  f16 v = (f16)h0[row * HIDn + col];
  h1b[i] = v;
  h2b[i] = v;
  if (i < 1024) ((int*)ws)[i] = 0;
}

/* ---- P1[v][g] = emb[v] . Wih1[g] + bih1[g] + bhh1[g]  (fp16) ---- */
__global__ void k_p1(const float* __restrict__ emb, const float* __restrict__ Wih1,
                     const float* __restrict__ bih1, const float* __restrict__ bhh1,
                     char* __restrict__ ws) {
  __shared__ float elds[32 * 256];
  int tid = threadIdx.x;
  int vb = blockIdx.x >> 5, gb = blockIdx.x & 31;  /* grid 512 */
  for (int i = tid; i < 32 * 256; i += 256) elds[i] = emb[vb * 32 * 256 + i];
  __syncthreads();
  int gl = tid & 63, vs = tid >> 6;
  int g = gb * 64 + gl;
  float bias = bih1[g] + bhh1[g];
  float acc[8];
#pragma unroll
  for (int r = 0; r < 8; ++r) acc[r] = bias;
  const float* wrow = Wih1 + g * EMBn;
#pragma unroll 4
  for (int e = 0; e < EMBn; ++e) {
    float w = wrow[e];
#pragma unroll
    for (int r = 0; r < 8; ++r) acc[r] += elds[(vs * 8 + r) * 256 + e] * w;
  }
  f16* P1 = (f16*)(ws + WS_P1);
#pragma unroll
  for (int r = 0; r < 8; ++r) P1[(vb * 32 + vs * 8 + r) * 2048 + g] = (f16)acc[r];
}

/* ---- persistent skewed-pipeline kernel: 4 independent batch groups ---- */
__global__ void __launch_bounds__(512, 2)
k_lstm(const int* __restrict__ x, const float* __restrict__ c0,
       const float* __restrict__ Whh1,
       const float* __restrict__ Wih2, const float* __restrict__ Whh2,
       const float* __restrict__ bih2, const float* __restrict__ bhh2,
       const float* __restrict__ Wfc, const float* __restrict__ bfc,
       float* __restrict__ out, char* __restrict__ ws)
{
  __shared__ float part[8][16][132];   /* per-wave partial gates, padded    */
  __shared__ alignas(16) f16 hstage[16][32];

  const int bid = blockIdx.x, tid = threadIdx.x;
  const int lane = tid & 63, wv = tid >> 6;
  const int cc = lane & 15, qq = lane >> 4;
  const int group = bid / GBLK, role = bid % GBLK;
  const int rp = role & 1;             /* read replica */

  f16* h1g = (f16*)(ws + WS_H1) + group * 4 * HS;
  f16* h2g = (f16*)(ws + WS_H2) + group * 4 * HS;
  const f16* P1 = (const f16*)(ws + WS_P1);
  int* flagp = (int*)ws + (group << 6) + role;

  half8 bfr[32];                       /* weight B-fragments, resident      */
  float cst = 0.f;                     /* epilogue cell state (1/thread)    */
  float biasr[4] = {0.f, 0.f, 0.f, 0.f};
  float bfcr = 0.f;
  float pgf[4] = {0.f, 0.f, 0.f, 0.f}; /* L1 pre-gathered P1 terms          */
  int j0 = 0;
  const int erow = tid >> 5, eu = tid & 31;   /* epilogue (row, unit/col)   */

  if (role < NL1g) {
    /* L1: 32 units; tiles nt: gate = nt>>1, unit = (nt&1)*16 + cc */
    j0 = role * 32;
#pragma unroll
    for (int nt = 0; nt < 8; ++nt) {
      const float* wr = Whh1 + ((nt >> 1) * 512 + j0 + (nt & 1) * 16 + cc) * HIDn;
#pragma unroll
      for (int kk = 0; kk < 2; ++kk) {
        const float* s = wr + (wv * 2 + kk) * 32 + qq * 8;
        half8 hv;
#pragma unroll
        for (int j = 0; j < 8; ++j) hv[j] = (f16)s[j];
        bfr[nt * 2 + kk] = hv;
      }
    }
    cst = c0[(group * 16 + erow) * HIDn + j0 + eu];
    /* pre-gather P1 terms for phase 1 */
    {
      const f16* pr = P1 + (size_t)x[group * 16 + erow] * 2048 + j0 + eu;
#pragma unroll
      for (int g = 0; g < 4; ++g) pgf[g] = (float)pr[g * 512];
    }
  } else if (role < NL1g + NL2g) {
    /* L2: 32 units; waves: kh = wv>>2 (h1/h2 source), kq = wv&3 (K quarter) */
    j0 = (role - NL1g) * 32;
    const int kh = wv >> 2, kq = wv & 3;
    const float* W = kh ? Whh2 : Wih2;
#pragma unroll
    for (int nt = 0; nt < 8; ++nt) {
      const float* wr = W + ((nt >> 1) * 512 + j0 + (nt & 1) * 16 + cc) * HIDn;
#pragma unroll
      for (int kk = 0; kk < 4; ++kk) {
        const float* s = wr + (kq * 4 + kk) * 32 + qq * 8;
        half8 hv;
#pragma unroll
        for (int j = 0; j < 8; ++j) hv[j] = (f16)s[j];
        bfr[nt * 4 + kk] = hv;
      }
    }
#pragma unroll
    for (int g = 0; g < 4; ++g)
      biasr[g] = bih2[g * 512 + j0 + eu] + bhh2[g * 512 + j0 + eu];
    cst = c0[(group * 16 + erow) * HIDn + j0 + eu];
  } else {
    /* FC: 32 vocab cols */
    j0 = (role - NL1g - NL2g) * 32;
#pragma unroll
    for (int nt = 0; nt < 2; ++nt) {
      const float* wr = Wfc + (j0 + nt * 16 + cc) * HIDn;
#pragma unroll
      for (int kk = 0; kk < 2; ++kk) {
        const float* s = wr + (wv * 2 + kk) * 32 + qq * 8;
        half8 hv;
#pragma unroll
        for (int j = 0; j < 8; ++j) hv[j] = (f16)s[j];
        bfr[nt * 2 + kk] = hv;
      }
    }
    bfcr = bfc[j0 + eu];
  }
  const int ks0 = j0 >> 5;
  __syncthreads();

  for (int p = 1; p <= NPHASE; ++p) {
    if (role < NL1g) {
      if (p <= SEQn) {                 /* h1_p = f(h1_{p-1}, x_{p-1}) */
        const f16* hp = h1g + (((p - 1) & 1) * 2 + rp) * HS;
        half8 a[2];
        ld2_sc1(hp + wv * 1024 + lane * 8, a);
        f32x4 acc[8];
#pragma unroll
        for (int nt = 0; nt < 8; ++nt)
#pragma unroll
          for (int r = 0; r < 4; ++r) acc[nt][r] = 0.f;
#pragma unroll
        for (int kk = 0; kk < 2; ++kk)
#pragma unroll
          for (int nt = 0; nt < 8; ++nt)
            acc[nt] = __builtin_amdgcn_mfma_f32_16x16x32_f16(a[kk], bfr[nt * 2 + kk], acc[nt], 0, 0, 0);
#pragma unroll
        for (int nt = 0; nt < 8; ++nt)
#pragma unroll
          for (int r = 0; r < 4; ++r)
            part[wv][qq * 4 + r][nt * 16 + cc] = acc[nt][r];
        __syncthreads();
        {
          float gs[4];
#pragma unroll
          for (int g = 0; g < 4; ++g) {
            float s = pgf[g];
#pragma unroll
            for (int kw = 0; kw < 8; ++kw) s += part[kw][erow][g * 32 + eu];
            gs[g] = s;
          }
          float cn = sigm_(gs[1]) * cst + sigm_(gs[0]) * tanh_(gs[2]);
          cst = cn;
          hstage[erow][eu] = (f16)(sigm_(gs[3]) * tanh_(cn));
        }
        __syncthreads();
        if (tid < 64) {
          f32x4 w = *(const f32x4*)&hstage[tid & 15][(tid >> 4) * 8];
          f16* ho = h1g + ((p & 1) * 2) * HS + ks0 * 512 + tid * 8;
          st_b128_sc1(ho, w);
          st_b128_sc1(ho + HS, w);
        }
      }
    } else if (role < NL1g + NL2g) {
      if (p >= 2 && p <= SEQn + 1) {   /* h2_{p-1} = f(h1_{p-1}, h2_{p-2}) */
        const int kh = wv >> 2, kq = wv & 3;
        const f16* src = kh ? h2g + ((p & 1) * 2 + rp) * HS
                            : h1g + (((p - 1) & 1) * 2 + rp) * HS;
        half8 a[4];
        ld4_sc1(src + kq * 2048 + lane * 8, a);
        f32x4 acc[8];
#pragma unroll
        for (int nt = 0; nt < 8; ++nt)
#pragma unroll
          for (int r = 0; r < 4; ++r) acc[nt][r] = 0.f;
#pragma unroll
        for (int kk = 0; kk < 4; ++kk)
#pragma unroll
          for (int nt = 0; nt < 8; ++nt)
            acc[nt] = __builtin_amdgcn_mfma_f32_16x16x32_f16(a[kk], bfr[nt * 4 + kk], acc[nt], 0, 0, 0);
#pragma unroll
        for (int nt = 0; nt < 8; ++nt)
#pragma unroll
          for (int r = 0; r < 4; ++r)
            part[wv][qq * 4 + r][nt * 16 + cc] = acc[nt][r];
        __syncthreads();
        {
          float gs[4];
#pragma unroll
          for (int g = 0; g < 4; ++g) {
            float s = biasr[g];
#pragma unroll
            for (int kw = 0; kw < 8; ++kw) s += part[kw][erow][g * 32 + eu];
            gs[g] = s;
          }
          float cn = sigm_(gs[1]) * cst + sigm_(gs[0]) * tanh_(gs[2]);
          cst = cn;
          hstage[erow][eu] = (f16)(sigm_(gs[3]) * tanh_(cn));
        }
        __syncthreads();
        if (tid < 64) {
          f32x4 w = *(const f32x4*)&hstage[tid & 15][(tid >> 4) * 8];
          f16* ho = h2g + (((p - 1) & 1) * 2) * HS + ks0 * 512 + tid * 8;
          st_b128_sc1(ho, w);
          st_b128_sc1(ho + HS, w);
        }
      }
    } else {
      if (p >= 3) {                    /* out_{p-3} = h2_{p-2} @ WfcT + bfc */
        const f16* hp = h2g + ((p & 1) * 2 + rp) * HS;
        half8 a[2];
        ld2_sc1(hp + wv * 1024 + lane * 8, a);
        f32x4 acc[2];
#pragma unroll
        for (int nt = 0; nt < 2; ++nt)
#pragma unroll
          for (int r = 0; r < 4; ++r) acc[nt][r] = 0.f;
#pragma unroll
        for (int kk = 0; kk < 2; ++kk)
#pragma unroll
          for (int nt = 0; nt < 2; ++nt)
            acc[nt] = __builtin_amdgcn_mfma_f32_16x16x32_f16(a[kk], bfr[nt * 2 + kk], acc[nt], 0, 0, 0);
#pragma unroll
        for (int nt = 0; nt < 2; ++nt)
#pragma unroll
          for (int r = 0; r < 4; ++r)
            part[wv][qq * 4 + r][nt * 16 + cc] = acc[nt][r];
        __syncthreads();
        {
          float s = bfcr;
#pragma unroll
          for (int kw = 0; kw < 8; ++kw) s += part[kw][erow][eu];
          float* op = out + (size_t)(p - 3) * (BATCHn * VOCn)
                    + (group * 16 + erow) * VOCn + j0 + eu;
          __builtin_nontemporal_store(s, op);
        }
      }
    }

    /* ---- group barrier: monotonic flag + 12-lane poll over 48 flags ----
       tid0 drains wave0's sc1 h-stores, then publishes the flag; other
       blocks' polls see flag=p only after the data is at the MALL.      */
    if (tid == 0) {
      asm volatile("s_waitcnt vmcnt(0)" ::: "memory");
      asm volatile("global_store_dword %0, %1, off sc1" :: "v"(flagp), "v"(p) : "memory");
    }
    /* L1: pre-gather next phase's P1 terms under the barrier wait */
    if (role < NL1g && p < SEQn) {
      const f16* pr = P1 + (size_t)x[p * 64 + group * 16 + erow] * 2048 + j0 + eu;
#pragma unroll
      for (int g = 0; g < 4; ++g) pgf[g] = (float)pr[g * 512];
    }
    if (wv == 0) {
      const int* fp = (const int*)ws + (group << 6) + (lane << 2);
      for (;;) {
        i32x4 f;
        asm volatile("global_load_dwordx4 %0, %1, off sc1\n\ts_waitcnt vmcnt(0)"
                     : "=v"(f) : "v"(fp) : "memory");
        int ok = (lane >= 12) ||
                 ((f[0] >= p) & (f[1] >= p) & (f[2] >= p) & (f[3] >= p));
        if (__all(ok)) break;
        __builtin_amdgcn_s_sleep(4);
      }
    }
    __syncthreads();
  }
}

extern "C" void kernel_launch(void* const* d_in, const int* in_sizes, int n_in,
                              void* d_out, int out_size, void* d_ws, size_t ws_size,
                              hipStream_t stream) {
  (void)in_sizes; (void)n_in; (void)out_size; (void)ws_size;
  const int*   x    = (const int*)  d_in[0];
  const float* h0   = (const float*)d_in[1];
  const float* c0   = (const float*)d_in[2];
  const float* emb  = (const float*)d_in[3];
  const float* Wih1 = (const float*)d_in[4];
  const float* Whh1 = (const float*)d_in[5];
  const float* bih1 = (const float*)d_in[6];
  const float* bhh1 = (const float*)d_in[7];
  const float* Wih2 = (const float*)d_in[8];
  const float* Whh2 = (const float*)d_in[9];
  const float* bih2 = (const float*)d_in[10];
  const float* bhh2 = (const float*)d_in[11];
  const float* Wfc  = (const float*)d_in[12];
  const float* bfc  = (const float*)d_in[13];
  char* ws = (char*)d_ws;

  hipLaunchKernelGGL(k_init, dim3(512), dim3(256), 0, stream, h0, ws);
  hipLaunchKernelGGL(k_p1,   dim3(512), dim3(256), 0, stream, emb, Wih1, bih1, bhh1, ws);
  hipLaunchKernelGGL(k_lstm, dim3(NBLK), dim3(512), 0, stream,
                     x, c0, Whh1, Wih2, Whh2, bih2, bhh2, Wfc, bfc,
                     (float*)d_out, ws);
}

// Round 6
// 4951.301 us; speedup vs baseline: 1.3344x; 1.0711x over previous
//
#include <hip/hip_runtime.h>

#define SEQn   1024
#define BATCHn 64
#define EMBn   256
#define HIDn   512
#define VOCn   512

#define NGRP 4                   /* independent batch groups of 16 rows      */
#define NL1g 16                  /* per group: 16 L1 blocks x 32 units       */
#define NL2g 16                  /* 16 L2 blocks x 32 units                  */
#define NFCg 16                  /* 16 FC blocks x 32 vocab cols             */
#define GBLK (NL1g + NL2g + NFCg)            /* 48 blocks per group          */
#define NBLK (NGRP * GBLK)                   /* 192 blocks, <= 256 CUs       */
#define NPHASE (SEQn + 2)        /* 1026 phases: skewed L1 / L2 / FC pipeline */
#define HS 8192                  /* f16 per h-slice: 16 rows x 512 = 16KB    */
#define NSLOT 4                  /* mod-4 timestep slots: classes may drift  */
#define THR_IGN (-1)             /* flags are >=0 -> always satisfied        */

using f16   = _Float16;
using half8 = __attribute__((ext_vector_type(8))) _Float16;
using f32x4 = __attribute__((ext_vector_type(4))) float;
using i32x4 = __attribute__((ext_vector_type(4))) int;

/* workspace layout (bytes) */
#define WS_FLG 0                 /* per group: 3 x 64B flag lines (L1,L2,FC) */
#define WS_H1  4096              /* [grp4][slot4][rep2][16KB] = 512KB        */
#define WS_H2  (WS_H1 + NGRP * NSLOT * 2 * HS * 2)
#define WS_P1  (WS_H2 + NGRP * NSLOT * 2 * HS * 2)   /* [512][2048] f16, 2MB */

/* ---- h-slice layout (per group slice, 16 rows x 512 cols) ----
   idx = ks*512 + qq*128 + cc*8 + e   <->  row = cc, col = ks*32 + qq*8 + e
   A-fragment load, lane l = qq*16+cc, slice ks: addr = ks*512 + l*8
   -> one lane-contiguous dwordx4 per ks (1KB per wave-instruction).       */

__device__ __forceinline__ float sigm_(float v) { return 1.0f / (1.0f + __expf(-v)); }
__device__ __forceinline__ float tanh_(float v) { return 1.0f - 2.0f / (__expf(2.0f * v) + 1.0f); }

__device__ __forceinline__ void st_b128_sc1(f16* p, f32x4 v) {
  asm volatile("global_store_dwordx4 %0, %1, off sc1" :: "v"(p), "v"(v) : "memory");
}

/* device-scope loads + drain inside ONE asm block (compiler cannot hoist a
   consumer past the internal s_waitcnt). Each covers this wave's K-slices. */
__device__ __forceinline__ void ld2_sc1(const f16* base, half8 (&a)[2]) {
  f32x4 t0, t1;
  asm volatile(
    "global_load_dwordx4 %0, %2, off sc1\n\t"
    "global_load_dwordx4 %1, %2, off offset:1024 sc1\n\t"
    "s_waitcnt vmcnt(0)"
    : "=&v"(t0), "=&v"(t1) : "v"(base) : "memory");
  a[0] = __builtin_bit_cast(half8, t0);
  a[1] = __builtin_bit_cast(half8, t1);
}
__device__ __forceinline__ void ld4_sc1(const f16* base, half8 (&a)[4]) {
  f32x4 t0, t1, t2, t3;
  asm volatile(
    "global_load_dwordx4 %0, %4, off sc1\n\t"
    "global_load_dwordx4 %1, %4, off offset:1024 sc1\n\t"
    "global_load_dwordx4 %2, %4, off offset:2048 sc1\n\t"
    "global_load_dwordx4 %3, %4, off offset:3072 sc1\n\t"
    "s_waitcnt vmcnt(0)"
    : "=&v"(t0), "=&v"(t1), "=&v"(t2), "=&v"(t3) : "v"(base) : "memory");
  a[0] = __builtin_bit_cast(half8, t0);
  a[1] = __builtin_bit_cast(half8, t1);
  a[2] = __builtin_bit_cast(half8, t2);
  a[3] = __builtin_bit_cast(half8, t3);
}

/* ---- init: zero flags, seed slot-0 h1/h2 slices (both replicas) ---- */
__global__ void k_init(const float* __restrict__ h0, char* __restrict__ ws) {
  int i = blockIdx.x * 256 + threadIdx.x;          /* grid 128*256 = 32768 */
  f16* h1b = (f16*)(ws + WS_H1);
  f16* h2b = (f16*)(ws + WS_H2);
  int g = i >> 13;                     /* 4 groups x 8192 slice elements    */
  int off = i & (HS - 1);
  int ks = off >> 9, rem = off & 511;
  int qq = rem >> 7, cc = (rem >> 3) & 15, e = rem & 7;
  int row = g * 16 + cc, col = ks * 32 + qq * 8 + e;
  f16 v = (f16)h0[row * HIDn + col];
  int base = g * (NSLOT * 2 * HS);                 /* slot 0 */
  h1b[base + off] = v;  h1b[base + HS + off] = v;
  h2b[base + off] = v;  h2b[base + HS + off] = v;
  if (i < 256) ((int*)ws)[i] = 0;
}

/* ---- P1[v][g] = emb[v] . Wih1[g] + bih1[g] + bhh1[g]  (fp16) ---- */
__global__ void k_p1(const float* __restrict__ emb, const float* __restrict__ Wih1,
                     const float* __restrict__ bih1, const float* __restrict__ bhh1,
                     char* __restrict__ ws) {
  __shared__ float elds[32 * 256];
  int tid = threadIdx.x;
  int vb = blockIdx.x >> 5, gb = blockIdx.x & 31;  /* grid 512 */
  for (int i = tid; i < 32 * 256; i += 256) elds[i] = emb[vb * 32 * 256 + i];
  __syncthreads();
  int gl = tid & 63, vs = tid >> 6;
  int g = gb * 64 + gl;
  float bias = bih1[g] + bhh1[g];
  float acc[8];
#pragma unroll
  for (int r = 0; r < 8; ++r) acc[r] = bias;
  const float* wrow = Wih1 + g * EMBn;
#pragma unroll 4
  for (int e = 0; e < EMBn; ++e) {
    float w = wrow[e];
#pragma unroll
    for (int r = 0; r < 8; ++r) acc[r] += elds[(vs * 8 + r) * 256 + e] * w;
  }
  f16* P1 = (f16*)(ws + WS_P1);
#pragma unroll
  for (int r = 0; r < 8; ++r) P1[(vb * 32 + vs * 8 + r) * 2048 + g] = (f16)acc[r];
}

/* ---- persistent skewed-pipeline kernel: 4 groups x 3 decoupled classes ---- */
__global__ void __launch_bounds__(512, 2)
k_lstm(const int* __restrict__ x, const float* __restrict__ c0,
       const float* __restrict__ Whh1,
       const float* __restrict__ Wih2, const float* __restrict__ Whh2,
       const float* __restrict__ bih2, const float* __restrict__ bhh2,
       const float* __restrict__ Wfc, const float* __restrict__ bfc,
       float* __restrict__ out, char* __restrict__ ws)
{
  __shared__ float part[8][16][132];   /* per-wave partial gates, padded    */
  __shared__ alignas(16) f16 hstage[16][32];

  const int bid = blockIdx.x, tid = threadIdx.x;
  const int lane = tid & 63, wv = tid >> 6;
  const int cc = lane & 15, qq = lane >> 4;
  const int group = bid / GBLK, role = bid % GBLK;

  f16* h1g = (f16*)(ws + WS_H1) + group * (NSLOT * 2 * HS);
  f16* h2g = (f16*)(ws + WS_H2) + group * (NSLOT * 2 * HS);
  const f16* P1 = (const f16*)(ws + WS_P1);
  /* class flag lines: [group][cls] = 16 ints each (one 64B line) */
  const int cls = (role < NL1g) ? 0 : (role < NL1g + NL2g) ? 1 : 2;
  int* flagp = (int*)ws + (group << 6) + (cls << 4) + (role & 15);

  half8 bfr[32];                       /* weight B-fragments, resident      */
  float cst = 0.f;                     /* epilogue cell state (1/thread)    */
  float biasr[4] = {0.f, 0.f, 0.f, 0.f};
  float bfcr = 0.f;
  float pgf[4] = {0.f, 0.f, 0.f, 0.f}; /* L1 pre-gathered P1 terms          */
  int j0 = 0;
  const int erow = tid >> 5, eu = tid & 31;   /* epilogue (row, unit/col)   */

  if (cls == 0) {
    /* L1: 32 units; tiles nt: gate = nt>>1, unit = (nt&1)*16 + cc */
    j0 = role * 32;
#pragma unroll
    for (int nt = 0; nt < 8; ++nt) {
      const float* wr = Whh1 + ((nt >> 1) * 512 + j0 + (nt & 1) * 16 + cc) * HIDn;
#pragma unroll
      for (int kk = 0; kk < 2; ++kk) {
        const float* s = wr + (wv * 2 + kk) * 32 + qq * 8;
        half8 hv;
#pragma unroll
        for (int j = 0; j < 8; ++j) hv[j] = (f16)s[j];
        bfr[nt * 2 + kk] = hv;
      }
    }
    cst = c0[(group * 16 + erow) * HIDn + j0 + eu];
    /* pre-gather P1 terms for phase 1 */
    {
      const f16* pr = P1 + (size_t)x[group * 16 + erow] * 2048 + j0 + eu;
#pragma unroll
      for (int g = 0; g < 4; ++g) pgf[g] = (float)pr[g * 512];
    }
  } else if (cls == 1) {
    /* L2: 32 units; waves: kh = wv>>2 (h1/h2 source), kq = wv&3 (K quarter) */
    j0 = (role - NL1g) * 32;
    const int kh = wv >> 2, kq = wv & 3;
    const float* W = kh ? Whh2 : Wih2;
#pragma unroll
    for (int nt = 0; nt < 8; ++nt) {
      const float* wr = W + ((nt >> 1) * 512 + j0 + (nt & 1) * 16 + cc) * HIDn;
#pragma unroll
      for (int kk = 0; kk < 4; ++kk) {
        const float* s = wr + (kq * 4 + kk) * 32 + qq * 8;
        half8 hv;
#pragma unroll
        for (int j = 0; j < 8; ++j) hv[j] = (f16)s[j];
        bfr[nt * 4 + kk] = hv;
      }
    }
#pragma unroll
    for (int g = 0; g < 4; ++g)
      biasr[g] = bih2[g * 512 + j0 + eu] + bhh2[g * 512 + j0 + eu];
    cst = c0[(group * 16 + erow) * HIDn + j0 + eu];
  } else {
    /* FC: 32 vocab cols */
    j0 = (role - NL1g - NL2g) * 32;
#pragma unroll
    for (int nt = 0; nt < 2; ++nt) {
      const float* wr = Wfc + (j0 + nt * 16 + cc) * HIDn;
#pragma unroll
      for (int kk = 0; kk < 2; ++kk) {
        const float* s = wr + (wv * 2 + kk) * 32 + qq * 8;
        half8 hv;
#pragma unroll
        for (int j = 0; j < 8; ++j) hv[j] = (f16)s[j];
        bfr[nt * 2 + kk] = hv;
      }
    }
    bfcr = bfc[j0 + eu];
  }
  const int ks0 = j0 >> 5;
  __syncthreads();

  for (int p = 1; p <= NPHASE; ++p) {
    if (cls == 0) {
      if (p <= SEQn) {                 /* h1_p = f(h1_{p-1}, x_{p-1}) */
        /* read h1_{p-1}: slot (p-1)&3, replica 0 (L1-private copy) */
        const f16* hp = h1g + ((p - 1) & 3) * (2 * HS);
        half8 a[2];
        ld2_sc1(hp + wv * 1024 + lane * 8, a);
        f32x4 acc[8];
#pragma unroll
        for (int nt = 0; nt < 8; ++nt)
#pragma unroll
          for (int r = 0; r < 4; ++r) acc[nt][r] = 0.f;
#pragma unroll
        for (int kk = 0; kk < 2; ++kk)
#pragma unroll
          for (int nt = 0; nt < 8; ++nt)
            acc[nt] = __builtin_amdgcn_mfma_f32_16x16x32_f16(a[kk], bfr[nt * 2 + kk], acc[nt], 0, 0, 0);
#pragma unroll
        for (int nt = 0; nt < 8; ++nt)
#pragma unroll
          for (int r = 0; r < 4; ++r)
            part[wv][qq * 4 + r][nt * 16 + cc] = acc[nt][r];
        __syncthreads();
        {
          float gs[4];
#pragma unroll
          for (int g = 0; g < 4; ++g) {
            float s = pgf[g];
#pragma unroll
            for (int kw = 0; kw < 8; ++kw) s += part[kw][erow][g * 32 + eu];
            gs[g] = s;
          }
          float cn = sigm_(gs[1]) * cst + sigm_(gs[0]) * tanh_(gs[2]);
          cst = cn;
          hstage[erow][eu] = (f16)(sigm_(gs[3]) * tanh_(cn));
        }
        __syncthreads();
        if (tid < 64) {
          f32x4 w = *(const f32x4*)&hstage[tid & 15][(tid >> 4) * 8];
          f16* ho = h1g + (p & 3) * (2 * HS) + ks0 * 512 + tid * 8;
          st_b128_sc1(ho, w);          /* replica 0 */
          st_b128_sc1(ho + HS, w);     /* replica 1 */
        }
      }
    } else if (cls == 1) {
      if (p >= 2 && p <= SEQn + 1) {   /* h2_{p-1} = f(h1_{p-1}, h2_{p-2}) */
        const int kh = wv >> 2, kq = wv & 3;
        /* h1_{p-1}: slot (p-1)&3 rep1; h2_{p-2}: slot (p-2)&3 rep0 */
        const f16* src = kh ? h2g + ((p - 2) & 3) * (2 * HS)
                            : h1g + ((p - 1) & 3) * (2 * HS) + HS;
        half8 a[4];
        ld4_sc1(src + kq * 2048 + lane * 8, a);
        f32x4 acc[8];
#pragma unroll
        for (int nt = 0; nt < 8; ++nt)
#pragma unroll
          for (int r = 0; r < 4; ++r) acc[nt][r] = 0.f;
#pragma unroll
        for (int kk = 0; kk < 4; ++kk)
#pragma unroll
          for (int nt = 0; nt < 8; ++nt)
            acc[nt] = __builtin_amdgcn_mfma_f32_16x16x32_f16(a[kk], bfr[nt * 4 + kk], acc[nt], 0, 0, 0);
#pragma unroll
        for (int nt = 0; nt < 8; ++nt)
#pragma unroll
          for (int r = 0; r < 4; ++r)
            part[wv][qq * 4 + r][nt * 16 + cc] = acc[nt][r];
        __syncthreads();
        {
          float gs[4];
#pragma unroll
          for (int g = 0; g < 4; ++g) {
            float s = biasr[g];
#pragma unroll
            for (int kw = 0; kw < 8; ++kw) s += part[kw][erow][g * 32 + eu];
            gs[g] = s;
          }
          float cn = sigm_(gs[1]) * cst + sigm_(gs[0]) * tanh_(gs[2]);
          cst = cn;
          hstage[erow][eu] = (f16)(sigm_(gs[3]) * tanh_(cn));
        }
        __syncthreads();
        if (tid < 64) {
          f32x4 w = *(const f32x4*)&hstage[tid & 15][(tid >> 4) * 8];
          f16* ho = h2g + ((p - 1) & 3) * (2 * HS) + ks0 * 512 + tid * 8;
          st_b128_sc1(ho, w);          /* replica 0 */
          st_b128_sc1(ho + HS, w);     /* replica 1 */
        }
      }
    } else {
      if (p >= 3) {                    /* out_{p-3} = h2_{p-2} @ WfcT + bfc */
        /* h2_{p-2}: slot (p-2)&3, replica 1 (FC-private copy) */
        const f16* hp = h2g + ((p - 2) & 3) * (2 * HS) + HS;
        half8 a[2];
        ld2_sc1(hp + wv * 1024 + lane * 8, a);
        f32x4 acc[2];
#pragma unroll
        for (int nt = 0; nt < 2; ++nt)
#pragma unroll
          for (int r = 0; r < 4; ++r) acc[nt][r] = 0.f;
#pragma unroll
        for (int kk = 0; kk < 2; ++kk)
#pragma unroll
          for (int nt = 0; nt < 2; ++nt)
            acc[nt] = __builtin_amdgcn_mfma_f32_16x16x32_f16(a[kk], bfr[nt * 2 + kk], acc[nt], 0, 0, 0);
#pragma unroll
        for (int nt = 0; nt < 2; ++nt)
#pragma unroll
          for (int r = 0; r < 4; ++r)
            part[wv][qq * 4 + r][nt * 16 + cc] = acc[nt][r];
        __syncthreads();
        {
          float s = bfcr;
#pragma unroll
          for (int kw = 0; kw < 8; ++kw) s += part[kw][erow][eu];
          float* op = out + (size_t)(p - 3) * (BATCHn * VOCn)
                    + (group * 16 + erow) * VOCn + j0 + eu;
          __builtin_nontemporal_store(s, op);
        }
      }
    }

    /* ---- decoupled class barrier ----
       publish: L1/L2 drain sc1 h-stores (wave 0 issued them), then ONE sc1
       flag store; FC skips the drain (out has no in-kernel reader).
       poll (wave 0, lanes 0-11, one 64B line per class):
         L1 : L1flags >= p       (h1_p ready)     | L2flags >= p-2 (slot safety)
         L2 : L1flags >= p  L2flags >= p          | FCflags >= p-2 (slot safety)
         FC :            L2flags >= p  (h2_{p-1} ready)
       mod-4 slots allow up to 3 phases of class drift -> stragglers in one
       class no longer stall the other classes' self-loop chains.           */
    if (tid == 0) {
      if (cls != 2) asm volatile("s_waitcnt vmcnt(0)" ::: "memory");
      asm volatile("global_store_dword %0, %1, off sc1" :: "v"(flagp), "v"(p) : "memory");
    }
    /* L1: pre-gather next phase's P1 terms under the barrier wait */
    if (cls == 0 && p < SEQn) {
      const f16* pr = P1 + (size_t)x[p * 64 + group * 16 + erow] * 2048 + j0 + eu;
#pragma unroll
      for (int g = 0; g < 4; ++g) pgf[g] = (float)pr[g * 512];
    }
    if (wv == 0) {
      int line = lane >> 2;
      int lc = (line < 3) ? line : 0;
      const int* fp = (const int*)ws + (group << 6) + (lc << 4) + ((lane & 3) << 2);
      int thr;
      if (cls == 0)      thr = (line == 0) ? p : (line == 1 ? p - 2 : THR_IGN);
      else if (cls == 1) thr = (line == 0) ? p : (line == 1 ? p : (line == 2 ? p - 2 : THR_IGN));
      else               thr = (line == 1) ? p : THR_IGN;
      if (line >= 3) thr = THR_IGN;
      for (;;) {
        i32x4 f;
        asm volatile("global_load_dwordx4 %0, %1, off sc1\n\ts_waitcnt vmcnt(0)"
                     : "=v"(f) : "v"(fp) : "memory");
        int ok = (f[0] >= thr) & (f[1] >= thr) & (f[2] >= thr) & (f[3] >= thr);
        if (__all(ok)) break;
        __builtin_amdgcn_s_sleep(1);
      }
    }
    __syncthreads();
  }
}

extern "C" void kernel_launch(void* const* d_in, const int* in_sizes, int n_in,
                              void* d_out, int out_size, void* d_ws, size_t ws_size,
                              hipStream_t stream) {
  (void)in_sizes; (void)n_in; (void)out_size; (void)ws_size;
  const int*   x    = (const int*)  d_in[0];
  const float* h0   = (const float*)d_in[1];
  const float* c0   = (const float*)d_in[2];
  const float* emb  = (const float*)d_in[3];
  const float* Wih1 = (const float*)d_in[4];
  const float* Whh1 = (const float*)d_in[5];
  const float* bih1 = (const float*)d_in[6];
  const float* bhh1 = (const float*)d_in[7];
  const float* Wih2 = (const float*)d_in[8];
  const float* Whh2 = (const float*)d_in[9];
  const float* bih2 = (const float*)d_in[10];
  const float* bhh2 = (const float*)d_in[11];
  const float* Wfc  = (const float*)d_in[12];
  const float* bfc  = (const float*)d_in[13];
  char* ws = (char*)d_ws;

  hipLaunchKernelGGL(k_init, dim3(128), dim3(256), 0, stream, h0, ws);
  hipLaunchKernelGGL(k_p1,   dim3(512), dim3(256), 0, stream, emb, Wih1, bih1, bhh1, ws);
  hipLaunchKernelGGL(k_lstm, dim3(NBLK), dim3(512), 0, stream,
                     x, c0, Whh1, Wih2, Whh2, bih2, bhh2, Wfc, bfc,
                     (float*)d_out, ws);
}